// Round 7
// baseline (372.036 us; speedup 1.0000x reference)
//
#include <hip/hip_runtime.h>
#include <hip/hip_bf16.h>
#include <math.h>

#define B_ 8
#define C_ 128
#define P_ 100000
#define K_ 14
#define H_ 8
#define DH_ 16
#define C2_ (2*C_)
#define E3_ (3*C_)
#define R2 0.25f

typedef float f32x4_t __attribute__((ext_vector_type(4)));
typedef __fp16 h2_t __attribute__((ext_vector_type(2)));

// -------------------- kernel 1: geometry -> u16 mask + nearest + counts --------------------
__global__ void geom_kernel(const float* __restrict__ pts,
                            const float* __restrict__ cav,
                            unsigned short* __restrict__ mask,
                            unsigned char* __restrict__ nearest,
                            int* __restrict__ counts) {
    __shared__ float cx[K_], cy[K_], cz[K_];
    __shared__ int sm[K_];
    int tid = threadIdx.x;
    if (tid < K_) {
        cx[tid] = cav[tid*3+0];
        cy[tid] = cav[tid*3+1];
        cz[tid] = cav[tid*3+2];
        sm[tid] = 0;
    }
    __syncthreads();
    int p = blockIdx.x * blockDim.x + tid;
    bool valid = (p < P_);
    int pc = valid ? p : (P_ - 1);
    float px = pts[pc*3+0], py = pts[pc*3+1], pz = pts[pc*3+2];
    unsigned m = 0;
    float best = 1e30f;
    int bi = 0;
    #pragma unroll
    for (int k = 0; k < K_; ++k) {
        float dx = px - cx[k], dy = py - cy[k], dz = pz - cz[k];
        float d2 = dx*dx + dy*dy + dz*dz;
        if (d2 < R2) m |= (1u << k);
        if (d2 < best) { best = d2; bi = k; }
    }
    if (valid) {
        mask[p] = (unsigned short)m;
        nearest[p] = (unsigned char)bi;
    }
    int lane = tid & 63;
    #pragma unroll
    for (int k = 0; k < K_; ++k) {
        unsigned long long bal = __ballot(valid && ((m >> k) & 1u));
        if (lane == 0) atomicAdd(&sm[k], (int)__popcll(bal));
    }
    __syncthreads();
    if (tid < K_) atomicAdd(&counts[tid], sm[tid]);
}

// -------------------- kernel 1b: expand u16 mask -> f16 {0,1} planes [K][P] --------------------
// each thread handles 2 points, writes one u32 (= half2) per plane
__global__ void expand_kernel(const unsigned short* __restrict__ mask,
                              unsigned int* __restrict__ planes) {
    int t = blockIdx.x * blockDim.x + threadIdx.x;
    if (t >= P_/2) return;
    unsigned m0 = mask[2*t], m1 = mask[2*t+1];
    #pragma unroll
    for (int k = 0; k < K_; ++k) {
        unsigned lo = ((m0 >> k) & 1u) ? 0x3C00u : 0u;       // f16 1.0
        unsigned hi = ((m1 >> k) & 1u) ? 0x3C000000u : 0u;
        planes[(size_t)k*(P_/2) + t] = lo | hi;
    }
}

// -------------------- kernel 2: masked pooling via v_dot2_f32_f16 --------------------
// grid = 256 blocks; 512 threads; each block owns 4 consecutive (b,c) rows.
__global__ __launch_bounds__(512) void pool_kernel(const float* __restrict__ x,
                                                   const unsigned int* __restrict__ planes,
                                                   float* __restrict__ sums) {
    int r0 = blockIdx.x * 4;
    int tid = threadIdx.x;
    const float4* xr0 = (const float4*)(x + (size_t)(r0+0) * P_);
    const float4* xr1 = (const float4*)(x + (size_t)(r0+1) * P_);
    const float4* xr2 = (const float4*)(x + (size_t)(r0+2) * P_);
    const float4* xr3 = (const float4*)(x + (size_t)(r0+3) * P_);
    float acc[4][K_];
    #pragma unroll
    for (int r = 0; r < 4; ++r)
        #pragma unroll
        for (int k = 0; k < K_; ++k) acc[r][k] = 0.f;
    for (int i = tid; i < P_/4; i += 512) {
        float4 xv0 = xr0[i], xv1 = xr1[i], xv2 = xr2[i], xv3 = xr3[i];
        // convert each row's 4 floats to 2 half2
        h2_t a0 = __builtin_amdgcn_cvt_pkrtz(xv0.x, xv0.y);
        h2_t b0 = __builtin_amdgcn_cvt_pkrtz(xv0.z, xv0.w);
        h2_t a1 = __builtin_amdgcn_cvt_pkrtz(xv1.x, xv1.y);
        h2_t b1 = __builtin_amdgcn_cvt_pkrtz(xv1.z, xv1.w);
        h2_t a2 = __builtin_amdgcn_cvt_pkrtz(xv2.x, xv2.y);
        h2_t b2 = __builtin_amdgcn_cvt_pkrtz(xv2.z, xv2.w);
        h2_t a3 = __builtin_amdgcn_cvt_pkrtz(xv3.x, xv3.y);
        h2_t b3 = __builtin_amdgcn_cvt_pkrtz(xv3.z, xv3.w);
        #pragma unroll
        for (int k = 0; k < K_; ++k) {
            uint2 mw = *(const uint2*)&planes[(size_t)k*(P_/2) + 2*i];  // masks for elems 4i..4i+3
            h2_t m01 = __builtin_bit_cast(h2_t, mw.x);
            h2_t m23 = __builtin_bit_cast(h2_t, mw.y);
            acc[0][k] = __builtin_amdgcn_fdot2(a0, m01, acc[0][k], false);
            acc[0][k] = __builtin_amdgcn_fdot2(b0, m23, acc[0][k], false);
            acc[1][k] = __builtin_amdgcn_fdot2(a1, m01, acc[1][k], false);
            acc[1][k] = __builtin_amdgcn_fdot2(b1, m23, acc[1][k], false);
            acc[2][k] = __builtin_amdgcn_fdot2(a2, m01, acc[2][k], false);
            acc[2][k] = __builtin_amdgcn_fdot2(b2, m23, acc[2][k], false);
            acc[3][k] = __builtin_amdgcn_fdot2(a3, m01, acc[3][k], false);
            acc[3][k] = __builtin_amdgcn_fdot2(b3, m23, acc[3][k], false);
        }
    }
    // wave butterfly reduce, then cross-wave via LDS
    int lane = tid & 63, wave = tid >> 6;
    __shared__ float lsum[8][4][K_];
    #pragma unroll
    for (int r = 0; r < 4; ++r) {
        #pragma unroll
        for (int k = 0; k < K_; ++k) {
            float v = acc[r][k];
            #pragma unroll
            for (int off = 32; off > 0; off >>= 1) v += __shfl_down(v, off);
            if (lane == 0) lsum[wave][r][k] = v;
        }
    }
    __syncthreads();
    if (tid < 4*K_) {
        int r = tid / K_, k = tid % K_;
        float t = 0.f;
        #pragma unroll
        for (int w = 0; w < 8; ++w) t += lsum[w][r][k];
        int row = r0 + r;
        int b = row >> 7, c = row & (C_-1);
        sums[((size_t)b*K_ + k)*C_ + c] = t;
    }
}

// -------------------- kernel 3: feat + per-cavity MLP + qkv projection --------------------
// grid = B*K blocks, 256 threads
__global__ void mlp_kernel(const float* __restrict__ sums,
                           const int* __restrict__ counts,
                           const float* __restrict__ w1,
                           const float* __restrict__ b1,
                           const float* __restrict__ w2,
                           const float* __restrict__ b2,
                           const float* __restrict__ in_w,
                           const float* __restrict__ in_b,
                           float* __restrict__ qkv_out) {
    int b = blockIdx.x / K_, k = blockIdx.x % K_;
    int tid = threadIdx.x;
    __shared__ float feat[C_];
    __shared__ float h[C2_];
    __shared__ float pr[C_];
    int cnt = counts[k];
    float inv = (cnt > 0) ? (1.f / (float)cnt) : 0.f;
    if (tid < C_) feat[tid] = sums[((size_t)b*K_ + k)*C_ + tid] * inv;
    __syncthreads();
    {
        const float* w1r = w1 + ((size_t)k*C2_ + tid)*C_;
        float a = b1[k*C2_ + tid];
        #pragma unroll 8
        for (int c = 0; c < C_; ++c) a += feat[c] * w1r[c];
        h[tid] = fmaxf(a, 0.f);
    }
    __syncthreads();
    if (tid < C_) {
        const float* w2r = w2 + ((size_t)k*C_ + tid)*C2_;
        float a = b2[k*C_ + tid];
        #pragma unroll 8
        for (int d = 0; d < C2_; ++d) a += h[d] * w2r[d];
        pr[tid] = tanhf(a);
    }
    __syncthreads();
    for (int e = tid; e < E3_; e += 256) {
        const float* wr = in_w + (size_t)e*C_;
        float a = in_b[e];
        #pragma unroll 8
        for (int c = 0; c < C_; ++c) a += pr[c] * wr[c];
        qkv_out[((size_t)b*K_ + k)*E3_ + e] = a;
    }
}

// -------------------- kernel 4: MHA over K cavities + out proj --------------------
// grid = B blocks, 256 threads
__global__ void attn_kernel(const float* __restrict__ qkv_in,
                            const float* __restrict__ out_w,
                            const float* __restrict__ out_b,
                            float* __restrict__ att) {
    int b = blockIdx.x;
    int tid = threadIdx.x;
    __shared__ float qkv[K_][E3_];
    __shared__ float ov[K_][C_];
    for (int i = tid; i < K_*E3_; i += 256) qkv[i / E3_][i % E3_] = qkv_in[(size_t)b*K_*E3_ + i];
    __syncthreads();
    if (tid < H_*K_) {
        int hh = tid / K_, q = tid % K_;
        const float* qv = &qkv[q][hh*DH_];
        float sc[K_];
        float mx = -1e30f;
        #pragma unroll
        for (int kk = 0; kk < K_; ++kk) {
            float a = 0.f;
            #pragma unroll
            for (int d = 0; d < DH_; ++d) a += qv[d] * qkv[kk][C_ + hh*DH_ + d];
            a *= 0.25f;
            sc[kk] = a;
            mx = fmaxf(mx, a);
        }
        float ssum = 0.f;
        #pragma unroll
        for (int kk = 0; kk < K_; ++kk) { sc[kk] = __expf(sc[kk] - mx); ssum += sc[kk]; }
        float rinv = 1.f / ssum;
        #pragma unroll
        for (int d = 0; d < DH_; ++d) {
            float a = 0.f;
            #pragma unroll
            for (int kk = 0; kk < K_; ++kk) a += sc[kk] * qkv[kk][2*C_ + hh*DH_ + d];
            ov[q][hh*DH_ + d] = a * rinv;
        }
    }
    __syncthreads();
    for (int i = tid; i < K_*C_; i += 256) {
        int kk = i / C_, o = i % C_;
        const float* wr = out_w + (size_t)o*C_;
        float a = out_b[o];
        #pragma unroll 8
        for (int c = 0; c < C_; ++c) a += ov[kk][c] * wr[c];
        att[((size_t)b*K_ + kk)*C_ + o] = a;
    }
}

// -------------------- kernel 5: gather-add, reverse-streamed, plain stores --------------------
// grid = (13, B*C), 256 threads
__global__ void gather_kernel(const float* __restrict__ x,
                              const float* __restrict__ att,
                              const unsigned char* __restrict__ nearest,
                              float* __restrict__ out) {
    int row = blockIdx.y;            // b*C + c
    int b = row >> 7, c = row & (C_-1);
    __shared__ float al[K_];
    if (threadIdx.x < K_) al[threadIdx.x] = att[((size_t)b*K_ + threadIdx.x)*C_ + c];
    __syncthreads();
    const float4* xr = (const float4*)(x + (size_t)row * P_);
    float4* orow = (float4*)(out + (size_t)row * P_);
    const uchar4* nr = (const uchar4*)nearest;
    for (int j = blockIdx.x * blockDim.x + threadIdx.x; j < P_/4; j += 13*256) {
        int i = P_/4 - 1 - j;        // tail-first: those lines are L3-resident from pool
        float4 xv = xr[i];
        uchar4 nv = nr[i];
        float4 o;
        o.x = xv.x + al[nv.x];
        o.y = xv.y + al[nv.y];
        o.z = xv.z + al[nv.z];
        o.w = xv.w + al[nv.w];
        orow[i] = o;
    }
}

extern "C" void kernel_launch(void* const* d_in, const int* in_sizes, int n_in,
                              void* d_out, int out_size, void* d_ws, size_t ws_size,
                              hipStream_t stream) {
    const float* x      = (const float*)d_in[0];
    const float* points = (const float*)d_in[1];
    const float* cav    = (const float*)d_in[2];
    const float* w1     = (const float*)d_in[3];
    const float* b1     = (const float*)d_in[4];
    const float* w2     = (const float*)d_in[5];
    const float* b2     = (const float*)d_in[6];
    const float* in_w   = (const float*)d_in[7];
    const float* in_b   = (const float*)d_in[8];
    const float* out_w  = (const float*)d_in[9];
    const float* out_b  = (const float*)d_in[10];
    float* out = (float*)d_out;

    // workspace carve (all offsets 256B-aligned)
    char* w = (char*)d_ws;
    unsigned short* mask    = (unsigned short*)(w + 0);        // 200,000 B
    unsigned char*  nearest = (unsigned char*)(w + 200192);    // 100,000 B
    int*            counts  = (int*)(w + 300288);              // 56 B
    float*          sums    = (float*)(w + 300544);            // 57,344 B
    float*          qkv     = (float*)(w + 358144);            // 172,032 B
    float*          att     = (float*)(w + 530432);            // 57,344 B
    unsigned int*   planes  = (unsigned int*)(w + 589824);     // 14*50000*4 = 2,800,000 B

    (void)hipMemsetAsync(counts, 0, K_ * sizeof(int), stream);
    geom_kernel<<<(P_ + 255)/256, 256, 0, stream>>>(points, cav, mask, nearest, counts);
    expand_kernel<<<(P_/2 + 255)/256, 256, 0, stream>>>(mask, planes);
    pool_kernel<<<256, 512, 0, stream>>>(x, planes, sums);
    mlp_kernel<<<B_*K_, 256, 0, stream>>>(sums, counts, w1, b1, w2, b2, in_w, in_b, qkv);
    attn_kernel<<<B_, 256, 0, stream>>>(qkv, out_w, out_b, att);
    gather_kernel<<<dim3(13, B_*C_), 256, 0, stream>>>(x, att, nearest, out);
}

// Round 8
// 359.216 us; speedup vs baseline: 1.0357x; 1.0357x over previous
//
#include <hip/hip_runtime.h>
#include <hip/hip_bf16.h>
#include <math.h>

#define B_ 8
#define C_ 128
#define P_ 100000
#define K_ 14
#define H_ 8
#define DH_ 16
#define C2_ (2*C_)
#define E3_ (3*C_)
#define R2 0.25f

typedef float f32x4_t __attribute__((ext_vector_type(4)));

__device__ __forceinline__ int bitsel(unsigned m, int k) {
#if __has_builtin(__builtin_amdgcn_sbfe)
    return __builtin_amdgcn_sbfe((int)m, (unsigned)k, 1u);
#else
    return ((int)(m << (31 - k))) >> 31;
#endif
}

// -------------------- kernel 1: geometry -> u16 mask + nearest + counts --------------------
__global__ void geom_kernel(const float* __restrict__ pts,
                            const float* __restrict__ cav,
                            unsigned short* __restrict__ mask,
                            unsigned char* __restrict__ nearest,
                            int* __restrict__ counts) {
    __shared__ float cx[K_], cy[K_], cz[K_];
    __shared__ int sm[K_];
    int tid = threadIdx.x;
    if (tid < K_) {
        cx[tid] = cav[tid*3+0];
        cy[tid] = cav[tid*3+1];
        cz[tid] = cav[tid*3+2];
        sm[tid] = 0;
    }
    __syncthreads();
    int p = blockIdx.x * blockDim.x + tid;
    bool valid = (p < P_);
    int pc = valid ? p : (P_ - 1);
    float px = pts[pc*3+0], py = pts[pc*3+1], pz = pts[pc*3+2];
    unsigned m = 0;
    float best = 1e30f;
    int bi = 0;
    #pragma unroll
    for (int k = 0; k < K_; ++k) {
        float dx = px - cx[k], dy = py - cy[k], dz = pz - cz[k];
        float d2 = dx*dx + dy*dy + dz*dz;
        if (d2 < R2) m |= (1u << k);
        if (d2 < best) { best = d2; bi = k; }
    }
    if (valid) {
        mask[p] = (unsigned short)m;
        nearest[p] = (unsigned char)bi;
    }
    int lane = tid & 63;
    #pragma unroll
    for (int k = 0; k < K_; ++k) {
        unsigned long long bal = __ballot(valid && ((m >> k) & 1u));
        if (lane == 0) atomicAdd(&sm[k], (int)__popcll(bal));
    }
    __syncthreads();
    if (tid < K_) atomicAdd(&counts[tid], sm[tid]);
}

// -------------------- kernel 2: masked pooling for one batch-group (4 batches = 512 rows) --------------------
// grid = 256 blocks (128 row-quads x 2 P-segments); 512 threads.
// Writes partials[seg*4+lb][k][c]; mlp reduces the 2 segments.
__global__ __launch_bounds__(512) void pool_kernel(const float* __restrict__ x,
                                                   const unsigned short* __restrict__ mask,
                                                   float* __restrict__ partials,
                                                   int row_base) {
    int quad = blockIdx.x >> 1;       // 0..127
    int seg  = blockIdx.x & 1;        // 0..1
    int r0 = row_base + quad*4;
    int tid = threadIdx.x;
    const float4* xr0 = (const float4*)(x + (size_t)(r0+0) * P_);
    const float4* xr1 = (const float4*)(x + (size_t)(r0+1) * P_);
    const float4* xr2 = (const float4*)(x + (size_t)(r0+2) * P_);
    const float4* xr3 = (const float4*)(x + (size_t)(r0+3) * P_);
    const ushort4* mr = (const ushort4*)mask;
    float acc[4][K_];
    #pragma unroll
    for (int r = 0; r < 4; ++r)
        #pragma unroll
        for (int k = 0; k < K_; ++k) acc[r][k] = 0.f;
    int i0 = seg * (P_/8);            // 12500 float4s per segment
    int i1 = i0 + (P_/8);
    for (int i = i0 + tid; i < i1; i += 512) {
        ushort4 mv = mr[i];
        unsigned ma = mv.x, mb = mv.y, mc = mv.z, md = mv.w;
        float4 xv0 = xr0[i], xv1 = xr1[i], xv2 = xr2[i], xv3 = xr3[i];
        #pragma unroll
        for (int k = 0; k < K_; ++k) {
            // decode bit k of 4 mask elems to 0.0f/1.0f once, reuse for 4 rows
            float m0 = __int_as_float(bitsel(ma, k) & 0x3f800000);
            float m1 = __int_as_float(bitsel(mb, k) & 0x3f800000);
            float m2 = __int_as_float(bitsel(mc, k) & 0x3f800000);
            float m3 = __int_as_float(bitsel(md, k) & 0x3f800000);
            acc[0][k] = fmaf(xv0.x, m0, fmaf(xv0.y, m1, fmaf(xv0.z, m2, fmaf(xv0.w, m3, acc[0][k]))));
            acc[1][k] = fmaf(xv1.x, m0, fmaf(xv1.y, m1, fmaf(xv1.z, m2, fmaf(xv1.w, m3, acc[1][k]))));
            acc[2][k] = fmaf(xv2.x, m0, fmaf(xv2.y, m1, fmaf(xv2.z, m2, fmaf(xv2.w, m3, acc[2][k]))));
            acc[3][k] = fmaf(xv3.x, m0, fmaf(xv3.y, m1, fmaf(xv3.z, m2, fmaf(xv3.w, m3, acc[3][k]))));
        }
    }
    // wave butterfly reduce, then cross-wave via LDS
    int lane = tid & 63, wave = tid >> 6;
    __shared__ float lsum[8][4][K_];
    #pragma unroll
    for (int r = 0; r < 4; ++r) {
        #pragma unroll
        for (int k = 0; k < K_; ++k) {
            float v = acc[r][k];
            #pragma unroll
            for (int off = 32; off > 0; off >>= 1) v += __shfl_down(v, off);
            if (lane == 0) lsum[wave][r][k] = v;
        }
    }
    __syncthreads();
    if (tid < 4*K_) {
        int r = tid / K_, k = tid % K_;
        float t = 0.f;
        #pragma unroll
        for (int w = 0; w < 8; ++w) t += lsum[w][r][k];
        int lrow = (r0 - row_base) + r;       // 0..511 within group
        int lb = lrow >> 7, c = lrow & (C_-1);
        partials[(((size_t)seg*4 + lb)*K_ + k)*C_ + c] = t;
    }
}

// -------------------- kernel 3: feat (reduce 2 segs) + per-cavity MLP + qkv --------------------
// grid = 4*K blocks (one group), 256 threads
__global__ void mlp_kernel(const float* __restrict__ partials,
                           const int* __restrict__ counts,
                           const float* __restrict__ w1,
                           const float* __restrict__ b1,
                           const float* __restrict__ w2,
                           const float* __restrict__ b2,
                           const float* __restrict__ in_w,
                           const float* __restrict__ in_b,
                           float* __restrict__ qkv_out,
                           int b_base) {
    int lb = blockIdx.x / K_, k = blockIdx.x % K_;
    int b = b_base + lb;
    int tid = threadIdx.x;
    __shared__ float feat[C_];
    __shared__ float h[C2_];
    __shared__ float pr[C_];
    int cnt = counts[k];
    float inv = (cnt > 0) ? (1.f / (float)cnt) : 0.f;
    if (tid < C_) {
        float s = partials[(((size_t)0*4 + lb)*K_ + k)*C_ + tid]
                + partials[(((size_t)1*4 + lb)*K_ + k)*C_ + tid];
        feat[tid] = s * inv;
    }
    __syncthreads();
    {
        const float* w1r = w1 + ((size_t)k*C2_ + tid)*C_;
        float a = b1[k*C2_ + tid];
        #pragma unroll 8
        for (int c = 0; c < C_; ++c) a += feat[c] * w1r[c];
        h[tid] = fmaxf(a, 0.f);
    }
    __syncthreads();
    if (tid < C_) {
        const float* w2r = w2 + ((size_t)k*C_ + tid)*C2_;
        float a = b2[k*C_ + tid];
        #pragma unroll 8
        for (int d = 0; d < C2_; ++d) a += h[d] * w2r[d];
        pr[tid] = tanhf(a);
    }
    __syncthreads();
    for (int e = tid; e < E3_; e += 256) {
        const float* wr = in_w + (size_t)e*C_;
        float a = in_b[e];
        #pragma unroll 8
        for (int c = 0; c < C_; ++c) a += pr[c] * wr[c];
        qkv_out[((size_t)b*K_ + k)*E3_ + e] = a;
    }
}

// -------------------- kernel 4: MHA over K cavities + out proj --------------------
// grid = 4 blocks (one group), 256 threads
__global__ void attn_kernel(const float* __restrict__ qkv_in,
                            const float* __restrict__ out_w,
                            const float* __restrict__ out_b,
                            float* __restrict__ att,
                            int b_base) {
    int b = b_base + blockIdx.x;
    int tid = threadIdx.x;
    __shared__ float qkv[K_][E3_];
    __shared__ float ov[K_][C_];
    for (int i = tid; i < K_*E3_; i += 256) qkv[i / E3_][i % E3_] = qkv_in[(size_t)b*K_*E3_ + i];
    __syncthreads();
    if (tid < H_*K_) {
        int hh = tid / K_, q = tid % K_;
        const float* qv = &qkv[q][hh*DH_];
        float sc[K_];
        float mx = -1e30f;
        #pragma unroll
        for (int kk = 0; kk < K_; ++kk) {
            float a = 0.f;
            #pragma unroll
            for (int d = 0; d < DH_; ++d) a += qv[d] * qkv[kk][C_ + hh*DH_ + d];
            a *= 0.25f;
            sc[kk] = a;
            mx = fmaxf(mx, a);
        }
        float ssum = 0.f;
        #pragma unroll
        for (int kk = 0; kk < K_; ++kk) { sc[kk] = __expf(sc[kk] - mx); ssum += sc[kk]; }
        float rinv = 1.f / ssum;
        #pragma unroll
        for (int d = 0; d < DH_; ++d) {
            float a = 0.f;
            #pragma unroll
            for (int kk = 0; kk < K_; ++kk) a += sc[kk] * qkv[kk][2*C_ + hh*DH_ + d];
            ov[q][hh*DH_ + d] = a * rinv;
        }
    }
    __syncthreads();
    for (int i = tid; i < K_*C_; i += 256) {
        int kk = i / C_, o = i % C_;
        const float* wr = out_w + (size_t)o*C_;
        float a = out_b[o];
        #pragma unroll 8
        for (int c = 0; c < C_; ++c) a += ov[kk][c] * wr[c];
        att[((size_t)b*K_ + kk)*C_ + o] = a;
    }
}

// -------------------- kernel 5: gather-add for one group, NT stores --------------------
// grid = (13, 512), 256 threads; x[group] should be L3-resident from pool(group)
__global__ void gather_kernel(const float* __restrict__ x,
                              const float* __restrict__ att,
                              const unsigned char* __restrict__ nearest,
                              float* __restrict__ out,
                              int row_base) {
    int row = row_base + blockIdx.y;
    int b = row >> 7, c = row & (C_-1);
    __shared__ float al[K_];
    if (threadIdx.x < K_) al[threadIdx.x] = att[((size_t)b*K_ + threadIdx.x)*C_ + c];
    __syncthreads();
    const float4* xr = (const float4*)(x + (size_t)row * P_);
    f32x4_t* orow = (f32x4_t*)(out + (size_t)row * P_);
    const uchar4* nr = (const uchar4*)nearest;
    for (int j = blockIdx.x * blockDim.x + threadIdx.x; j < P_/4; j += 13*256) {
        int i = P_/4 - 1 - j;        // tail-first
        float4 xv = xr[i];
        uchar4 nv = nr[i];
        f32x4_t o;
        o.x = xv.x + al[nv.x];
        o.y = xv.y + al[nv.y];
        o.z = xv.z + al[nv.z];
        o.w = xv.w + al[nv.w];
        __builtin_nontemporal_store(o, &orow[i]);
    }
}

extern "C" void kernel_launch(void* const* d_in, const int* in_sizes, int n_in,
                              void* d_out, int out_size, void* d_ws, size_t ws_size,
                              hipStream_t stream) {
    const float* x      = (const float*)d_in[0];
    const float* points = (const float*)d_in[1];
    const float* cav    = (const float*)d_in[2];
    const float* w1     = (const float*)d_in[3];
    const float* b1     = (const float*)d_in[4];
    const float* w2     = (const float*)d_in[5];
    const float* b2     = (const float*)d_in[6];
    const float* in_w   = (const float*)d_in[7];
    const float* in_b   = (const float*)d_in[8];
    const float* out_w  = (const float*)d_in[9];
    const float* out_b  = (const float*)d_in[10];
    float* out = (float*)d_out;

    // workspace carve (all offsets 256B-aligned)
    char* w = (char*)d_ws;
    unsigned short* mask    = (unsigned short*)(w + 0);        // 200,000 B
    unsigned char*  nearest = (unsigned char*)(w + 200192);    // 100,000 B
    int*            counts  = (int*)(w + 300288);              // 56 B
    float*          partials= (float*)(w + 300544);            // 2*4*14*128*4 = 57,344 B
    float*          qkv     = (float*)(w + 358144);            // 172,032 B
    float*          att     = (float*)(w + 530432);            // 57,344 B

    (void)hipMemsetAsync(counts, 0, K_ * sizeof(int), stream);
    geom_kernel<<<(P_ + 255)/256, 256, 0, stream>>>(points, cav, mask, nearest, counts);
    for (int g = 0; g < 2; ++g) {
        int row_base = g * 4 * C_;     // 512 rows per group
        int b_base   = g * 4;
        pool_kernel<<<256, 512, 0, stream>>>(x, mask, partials, row_base);
        mlp_kernel<<<4*K_, 256, 0, stream>>>(partials, counts, w1, b1, w2, b2, in_w, in_b, qkv, b_base);
        attn_kernel<<<4, 256, 0, stream>>>(qkv, out_w, out_b, att, b_base);
        gather_kernel<<<dim3(13, 4*C_), 256, 0, stream>>>(x, att, nearest, out, row_base);
    }
}

// Round 9
// 335.228 us; speedup vs baseline: 1.1098x; 1.0716x over previous
//
#include <hip/hip_runtime.h>
#include <hip/hip_bf16.h>
#include <math.h>

#define B_ 8
#define C_ 128
#define P_ 100000
#define K_ 14
#define H_ 8
#define DH_ 16
#define C2_ (2*C_)
#define E3_ (3*C_)
#define R2 0.25f

typedef float f32x4_t __attribute__((ext_vector_type(4)));

__device__ __forceinline__ int bitsel(unsigned m, int k) {
#if __has_builtin(__builtin_amdgcn_sbfe)
    return __builtin_amdgcn_sbfe((int)m, (unsigned)k, 1u);
#else
    return ((int)(m << (31 - k))) >> 31;
#endif
}

__device__ __forceinline__ unsigned short f2bf(float f) {
    __hip_bfloat16 h = __float2bfloat16(f);
    return *(unsigned short*)&h;
}

// -------------------- kernel 1: geometry -> u16 mask + nearest + counts --------------------
__global__ void geom_kernel(const float* __restrict__ pts,
                            const float* __restrict__ cav,
                            unsigned short* __restrict__ mask,
                            unsigned char* __restrict__ nearest,
                            int* __restrict__ counts) {
    __shared__ float cx[K_], cy[K_], cz[K_];
    __shared__ int sm[K_];
    int tid = threadIdx.x;
    if (tid < K_) {
        cx[tid] = cav[tid*3+0];
        cy[tid] = cav[tid*3+1];
        cz[tid] = cav[tid*3+2];
        sm[tid] = 0;
    }
    __syncthreads();
    int p = blockIdx.x * blockDim.x + tid;
    bool valid = (p < P_);
    int pc = valid ? p : (P_ - 1);
    float px = pts[pc*3+0], py = pts[pc*3+1], pz = pts[pc*3+2];
    unsigned m = 0;
    float best = 1e30f;
    int bi = 0;
    #pragma unroll
    for (int k = 0; k < K_; ++k) {
        float dx = px - cx[k], dy = py - cy[k], dz = pz - cz[k];
        float d2 = dx*dx + dy*dy + dz*dz;
        if (d2 < R2) m |= (1u << k);
        if (d2 < best) { best = d2; bi = k; }
    }
    if (valid) {
        mask[p] = (unsigned short)m;
        nearest[p] = (unsigned char)bi;
    }
    int lane = tid & 63;
    #pragma unroll
    for (int k = 0; k < K_; ++k) {
        unsigned long long bal = __ballot(valid && ((m >> k) & 1u));
        if (lane == 0) atomicAdd(&sm[k], (int)__popcll(bal));
    }
    __syncthreads();
    if (tid < K_) atomicAdd(&counts[tid], sm[tid]);
}

// -------------------- kernel 2: masked pooling, u16 decode shared over 4 rows --------------------
// grid = 256 blocks; 512 threads; each block owns 4 consecutive (b,c) rows.
// WRITE_COPY: also emit bf16 copy of x (for gather's second pass).
template<int WRITE_COPY>
__global__ __launch_bounds__(512) void pool_kernel(const float* __restrict__ x,
                                                   const unsigned short* __restrict__ mask,
                                                   float* __restrict__ sums,
                                                   unsigned short* __restrict__ xcopy) {
    int r0 = blockIdx.x * 4;
    int tid = threadIdx.x;
    const float4* xr0 = (const float4*)(x + (size_t)(r0+0) * P_);
    const float4* xr1 = (const float4*)(x + (size_t)(r0+1) * P_);
    const float4* xr2 = (const float4*)(x + (size_t)(r0+2) * P_);
    const float4* xr3 = (const float4*)(x + (size_t)(r0+3) * P_);
    uint2* c0 = (uint2*)(xcopy + (size_t)(r0+0) * P_);
    uint2* c1 = (uint2*)(xcopy + (size_t)(r0+1) * P_);
    uint2* c2 = (uint2*)(xcopy + (size_t)(r0+2) * P_);
    uint2* c3 = (uint2*)(xcopy + (size_t)(r0+3) * P_);
    const ushort4* mr = (const ushort4*)mask;
    float acc[4][K_];
    #pragma unroll
    for (int r = 0; r < 4; ++r)
        #pragma unroll
        for (int k = 0; k < K_; ++k) acc[r][k] = 0.f;
    for (int i = tid; i < P_/4; i += 512) {
        ushort4 mv = mr[i];
        unsigned ma = mv.x, mb = mv.y, mc = mv.z, md = mv.w;
        float4 xv0 = xr0[i], xv1 = xr1[i], xv2 = xr2[i], xv3 = xr3[i];
        if (WRITE_COPY) {
            uint2 w0, w1, w2, w3;
            w0.x = (unsigned)f2bf(xv0.x) | ((unsigned)f2bf(xv0.y) << 16);
            w0.y = (unsigned)f2bf(xv0.z) | ((unsigned)f2bf(xv0.w) << 16);
            w1.x = (unsigned)f2bf(xv1.x) | ((unsigned)f2bf(xv1.y) << 16);
            w1.y = (unsigned)f2bf(xv1.z) | ((unsigned)f2bf(xv1.w) << 16);
            w2.x = (unsigned)f2bf(xv2.x) | ((unsigned)f2bf(xv2.y) << 16);
            w2.y = (unsigned)f2bf(xv2.z) | ((unsigned)f2bf(xv2.w) << 16);
            w3.x = (unsigned)f2bf(xv3.x) | ((unsigned)f2bf(xv3.y) << 16);
            w3.y = (unsigned)f2bf(xv3.z) | ((unsigned)f2bf(xv3.w) << 16);
            c0[i] = w0; c1[i] = w1; c2[i] = w2; c3[i] = w3;
        }
        #pragma unroll
        for (int k = 0; k < K_; ++k) {
            float m0 = __int_as_float(bitsel(ma, k) & 0x3f800000);
            float m1 = __int_as_float(bitsel(mb, k) & 0x3f800000);
            float m2 = __int_as_float(bitsel(mc, k) & 0x3f800000);
            float m3 = __int_as_float(bitsel(md, k) & 0x3f800000);
            acc[0][k] = fmaf(xv0.x, m0, fmaf(xv0.y, m1, fmaf(xv0.z, m2, fmaf(xv0.w, m3, acc[0][k]))));
            acc[1][k] = fmaf(xv1.x, m0, fmaf(xv1.y, m1, fmaf(xv1.z, m2, fmaf(xv1.w, m3, acc[1][k]))));
            acc[2][k] = fmaf(xv2.x, m0, fmaf(xv2.y, m1, fmaf(xv2.z, m2, fmaf(xv2.w, m3, acc[2][k]))));
            acc[3][k] = fmaf(xv3.x, m0, fmaf(xv3.y, m1, fmaf(xv3.z, m2, fmaf(xv3.w, m3, acc[3][k]))));
        }
    }
    // wave butterfly reduce, then cross-wave via LDS
    int lane = tid & 63, wave = tid >> 6;
    __shared__ float lsum[8][4][K_];
    #pragma unroll
    for (int r = 0; r < 4; ++r) {
        #pragma unroll
        for (int k = 0; k < K_; ++k) {
            float v = acc[r][k];
            #pragma unroll
            for (int off = 32; off > 0; off >>= 1) v += __shfl_down(v, off);
            if (lane == 0) lsum[wave][r][k] = v;
        }
    }
    __syncthreads();
    if (tid < 4*K_) {
        int r = tid / K_, k = tid % K_;
        float t = 0.f;
        #pragma unroll
        for (int w = 0; w < 8; ++w) t += lsum[w][r][k];
        int row = r0 + r;
        int b = row >> 7, c = row & (C_-1);
        sums[((size_t)b*K_ + k)*C_ + c] = t;
    }
}

// -------------------- kernel 3: feat + per-cavity MLP + qkv projection --------------------
// grid = B*K blocks, 256 threads
__global__ void mlp_kernel(const float* __restrict__ sums,
                           const int* __restrict__ counts,
                           const float* __restrict__ w1,
                           const float* __restrict__ b1,
                           const float* __restrict__ w2,
                           const float* __restrict__ b2,
                           const float* __restrict__ in_w,
                           const float* __restrict__ in_b,
                           float* __restrict__ qkv_out) {
    int b = blockIdx.x / K_, k = blockIdx.x % K_;
    int tid = threadIdx.x;
    __shared__ float feat[C_];
    __shared__ float h[C2_];
    __shared__ float pr[C_];
    int cnt = counts[k];
    float inv = (cnt > 0) ? (1.f / (float)cnt) : 0.f;
    if (tid < C_) feat[tid] = sums[((size_t)b*K_ + k)*C_ + tid] * inv;
    __syncthreads();
    {
        const float* w1r = w1 + ((size_t)k*C2_ + tid)*C_;
        float a = b1[k*C2_ + tid];
        #pragma unroll 8
        for (int c = 0; c < C_; ++c) a += feat[c] * w1r[c];
        h[tid] = fmaxf(a, 0.f);
    }
    __syncthreads();
    if (tid < C_) {
        const float* w2r = w2 + ((size_t)k*C_ + tid)*C2_;
        float a = b2[k*C_ + tid];
        #pragma unroll 8
        for (int d = 0; d < C2_; ++d) a += h[d] * w2r[d];
        pr[tid] = tanhf(a);
    }
    __syncthreads();
    for (int e = tid; e < E3_; e += 256) {
        const float* wr = in_w + (size_t)e*C_;
        float a = in_b[e];
        #pragma unroll 8
        for (int c = 0; c < C_; ++c) a += pr[c] * wr[c];
        qkv_out[((size_t)b*K_ + k)*E3_ + e] = a;
    }
}

// -------------------- kernel 4: MHA over K cavities + out proj --------------------
// grid = B blocks, 256 threads
__global__ void attn_kernel(const float* __restrict__ qkv_in,
                            const float* __restrict__ out_w,
                            const float* __restrict__ out_b,
                            float* __restrict__ att) {
    int b = blockIdx.x;
    int tid = threadIdx.x;
    __shared__ float qkv[K_][E3_];
    __shared__ float ov[K_][C_];
    for (int i = tid; i < K_*E3_; i += 256) qkv[i / E3_][i % E3_] = qkv_in[(size_t)b*K_*E3_ + i];
    __syncthreads();
    if (tid < H_*K_) {
        int hh = tid / K_, q = tid % K_;
        const float* qv = &qkv[q][hh*DH_];
        float sc[K_];
        float mx = -1e30f;
        #pragma unroll
        for (int kk = 0; kk < K_; ++kk) {
            float a = 0.f;
            #pragma unroll
            for (int d = 0; d < DH_; ++d) a += qv[d] * qkv[kk][C_ + hh*DH_ + d];
            a *= 0.25f;
            sc[kk] = a;
            mx = fmaxf(mx, a);
        }
        float ssum = 0.f;
        #pragma unroll
        for (int kk = 0; kk < K_; ++kk) { sc[kk] = __expf(sc[kk] - mx); ssum += sc[kk]; }
        float rinv = 1.f / ssum;
        #pragma unroll
        for (int d = 0; d < DH_; ++d) {
            float a = 0.f;
            #pragma unroll
            for (int kk = 0; kk < K_; ++kk) a += sc[kk] * qkv[kk][2*C_ + hh*DH_ + d];
            ov[q][hh*DH_ + d] = a * rinv;
        }
    }
    __syncthreads();
    for (int i = tid; i < K_*C_; i += 256) {
        int kk = i / C_, o = i % C_;
        const float* wr = out_w + (size_t)o*C_;
        float a = out_b[o];
        #pragma unroll 8
        for (int c = 0; c < C_; ++c) a += ov[kk][c] * wr[c];
        att[((size_t)b*K_ + kk)*C_ + o] = a;
    }
}

// -------------------- kernel 5: gather-add, reverse-streamed, plain stores --------------------
// USE_COPY: read bf16 copy of x (half the read bytes; tail L3-hot from pool)
template<int USE_COPY>
__global__ void gather_kernel(const float* __restrict__ x,
                              const unsigned short* __restrict__ xcopy,
                              const float* __restrict__ att,
                              const unsigned char* __restrict__ nearest,
                              float* __restrict__ out) {
    int row = blockIdx.y;            // b*C + c
    int b = row >> 7, c = row & (C_-1);
    __shared__ float al[K_];
    if (threadIdx.x < K_) al[threadIdx.x] = att[((size_t)b*K_ + threadIdx.x)*C_ + c];
    __syncthreads();
    const float4* xr = (const float4*)(x + (size_t)row * P_);
    const uint2* cr = (const uint2*)(xcopy + (size_t)row * P_);
    float4* orow = (float4*)(out + (size_t)row * P_);
    const uchar4* nr = (const uchar4*)nearest;
    for (int j = blockIdx.x * blockDim.x + threadIdx.x; j < P_/4; j += 13*256) {
        int i = P_/4 - 1 - j;        // tail-first: matches pool's most-recent writes
        float x0, x1, x2, x3;
        if (USE_COPY) {
            uint2 cw = cr[i];
            x0 = __uint_as_float(cw.x << 16);
            x1 = __uint_as_float(cw.x & 0xffff0000u);
            x2 = __uint_as_float(cw.y << 16);
            x3 = __uint_as_float(cw.y & 0xffff0000u);
        } else {
            float4 xv = xr[i];
            x0 = xv.x; x1 = xv.y; x2 = xv.z; x3 = xv.w;
        }
        uchar4 nv = nr[i];
        float4 o;
        o.x = x0 + al[nv.x];
        o.y = x1 + al[nv.y];
        o.z = x2 + al[nv.z];
        o.w = x3 + al[nv.w];
        orow[i] = o;
    }
}

extern "C" void kernel_launch(void* const* d_in, const int* in_sizes, int n_in,
                              void* d_out, int out_size, void* d_ws, size_t ws_size,
                              hipStream_t stream) {
    const float* x      = (const float*)d_in[0];
    const float* points = (const float*)d_in[1];
    const float* cav    = (const float*)d_in[2];
    const float* w1     = (const float*)d_in[3];
    const float* b1     = (const float*)d_in[4];
    const float* w2     = (const float*)d_in[5];
    const float* b2     = (const float*)d_in[6];
    const float* in_w   = (const float*)d_in[7];
    const float* in_b   = (const float*)d_in[8];
    const float* out_w  = (const float*)d_in[9];
    const float* out_b  = (const float*)d_in[10];
    float* out = (float*)d_out;

    // workspace carve (all offsets 256B-aligned)
    char* w = (char*)d_ws;
    unsigned short* mask    = (unsigned short*)(w + 0);        // 200,000 B
    unsigned char*  nearest = (unsigned char*)(w + 200192);    // 100,000 B
    int*            counts  = (int*)(w + 300288);              // 56 B
    float*          sums    = (float*)(w + 300544);            // 57,344 B
    float*          qkv     = (float*)(w + 358144);            // 172,032 B
    float*          att     = (float*)(w + 530432);            // 57,344 B
    unsigned short* xcopy   = (unsigned short*)(w + 587776);   // 8*128*100000*2 = 204,800,000 B
    const size_t need = 587776ull + 204800000ull;
    bool use_copy = (ws_size >= need);

    (void)hipMemsetAsync(counts, 0, K_ * sizeof(int), stream);
    geom_kernel<<<(P_ + 255)/256, 256, 0, stream>>>(points, cav, mask, nearest, counts);
    if (use_copy)
        pool_kernel<1><<<256, 512, 0, stream>>>(x, mask, sums, xcopy);
    else
        pool_kernel<0><<<256, 512, 0, stream>>>(x, mask, sums, xcopy);
    mlp_kernel<<<B_*K_, 256, 0, stream>>>(sums, counts, w1, b1, w2, b2, in_w, in_b, qkv);
    attn_kernel<<<B_, 256, 0, stream>>>(qkv, out_w, out_b, att);
    if (use_copy)
        gather_kernel<1><<<dim3(13, B_*C_), 256, 0, stream>>>(x, xcopy, att, nearest, out);
    else
        gather_kernel<0><<<dim3(13, B_*C_), 256, 0, stream>>>(x, xcopy, att, nearest, out);
}

// Round 10
// 323.706 us; speedup vs baseline: 1.1493x; 1.0356x over previous
//
#include <hip/hip_runtime.h>
#include <hip/hip_bf16.h>
#include <math.h>

#define B_ 8
#define C_ 128
#define P_ 100000
#define K_ 14
#define H_ 8
#define DH_ 16
#define C2_ (2*C_)
#define E3_ (3*C_)
#define R2 0.25f

typedef short bf16x8 __attribute__((ext_vector_type(8)));
typedef float f32x4v __attribute__((ext_vector_type(4)));

__device__ __forceinline__ int bitsel(unsigned m, int k) {
#if __has_builtin(__builtin_amdgcn_sbfe)
    return __builtin_amdgcn_sbfe((int)m, (unsigned)k, 1u);
#else
    return ((int)(m << (31 - k))) >> 31;
#endif
}

__device__ __forceinline__ short f2bfs(float f) {
    __hip_bfloat16 h = __float2bfloat16(f);
    return *reinterpret_cast<short*>(&h);
}

// -------------------- kernel 1: geometry -> u16 mask + nearest + counts --------------------
__global__ void geom_kernel(const float* __restrict__ pts,
                            const float* __restrict__ cav,
                            unsigned short* __restrict__ mask,
                            unsigned char* __restrict__ nearest,
                            int* __restrict__ counts) {
    __shared__ float cx[K_], cy[K_], cz[K_];
    __shared__ int sm[K_];
    int tid = threadIdx.x;
    if (tid < K_) {
        cx[tid] = cav[tid*3+0];
        cy[tid] = cav[tid*3+1];
        cz[tid] = cav[tid*3+2];
        sm[tid] = 0;
    }
    __syncthreads();
    int p = blockIdx.x * blockDim.x + tid;
    bool valid = (p < P_);
    int pc = valid ? p : (P_ - 1);
    float px = pts[pc*3+0], py = pts[pc*3+1], pz = pts[pc*3+2];
    unsigned m = 0;
    float best = 1e30f;
    int bi = 0;
    #pragma unroll
    for (int k = 0; k < K_; ++k) {
        float dx = px - cx[k], dy = py - cy[k], dz = pz - cz[k];
        float d2 = dx*dx + dy*dy + dz*dz;
        if (d2 < R2) m |= (1u << k);
        if (d2 < best) { best = d2; bi = k; }
    }
    if (valid) {
        mask[p] = (unsigned short)m;
        nearest[p] = (unsigned char)bi;
    }
    int lane = tid & 63;
    #pragma unroll
    for (int k = 0; k < K_; ++k) {
        unsigned long long bal = __ballot(valid && ((m >> k) & 1u));
        if (lane == 0) atomicAdd(&sm[k], (int)__popcll(bal));
    }
    __syncthreads();
    if (tid < K_) atomicAdd(&counts[tid], sm[tid]);
}

// -------------------- kernel 2: masked pooling via MFMA --------------------
// sums[b,k,c] = sum_p x[b,c,p]*maskbit[k,p]  == A[c-rows x P] * B[P x 14]
// grid = 256 blocks (32 c-group-pairs x 8 P-splits), 256 threads (4 waves).
// Each wave: 2 MFMA tiles (2 c-groups of 16 rows) per 32-p step.
// A: lane holds x[c0 + (lane&15)][p0 + (lane>>4)*8 + e]  (bf16)
// B: lane holds maskbit[p0 + (lane>>4)*8 + e][lane&15]   (bf16 0/1)
// (k-slot assignment is consistent between A and B, so any A/B-symmetric
//  hardware k-layout contracts correctly; C/D: col=lane&15, row=(lane>>4)*4+reg)
__global__ __launch_bounds__(256) void pool_mfma_kernel(const float* __restrict__ x,
                                                        const unsigned short* __restrict__ mask,
                                                        float* __restrict__ partials) {
    int gpair = blockIdx.x & 31;       // c-groups 2*gpair, 2*gpair+1 (16 rows each)
    int split = blockIdx.x >> 5;       // 0..7
    int tid = threadIdx.x;
    int wave = tid >> 6, lane = tid & 63;
    int lrow = lane & 15, lgrp = lane >> 4;
    int stripe = split*4 + wave;       // 0..31
    const float* xr0 = x + (size_t)((2*gpair+0)*16 + lrow) * P_;
    const float* xr1 = x + (size_t)((2*gpair+1)*16 + lrow) * P_;
    f32x4v acc0 = {0.f,0.f,0.f,0.f}, acc1 = {0.f,0.f,0.f,0.f};
    for (int t = stripe; t < P_/32; t += 32) {
        int p0 = t*32 + lgrp*8;
        ushort4 mw0 = *(const ushort4*)(mask + p0);
        ushort4 mw1 = *(const ushort4*)(mask + p0 + 4);
        float4 xa = *(const float4*)(xr0 + p0);
        float4 xb = *(const float4*)(xr0 + p0 + 4);
        float4 xc = *(const float4*)(xr1 + p0);
        float4 xd = *(const float4*)(xr1 + p0 + 4);
        bf16x8 bfr, a0, a1;
        bfr[0] = (short)(bitsel(mw0.x, lrow) & 0x3F80);
        bfr[1] = (short)(bitsel(mw0.y, lrow) & 0x3F80);
        bfr[2] = (short)(bitsel(mw0.z, lrow) & 0x3F80);
        bfr[3] = (short)(bitsel(mw0.w, lrow) & 0x3F80);
        bfr[4] = (short)(bitsel(mw1.x, lrow) & 0x3F80);
        bfr[5] = (short)(bitsel(mw1.y, lrow) & 0x3F80);
        bfr[6] = (short)(bitsel(mw1.z, lrow) & 0x3F80);
        bfr[7] = (short)(bitsel(mw1.w, lrow) & 0x3F80);
        a0[0] = f2bfs(xa.x); a0[1] = f2bfs(xa.y); a0[2] = f2bfs(xa.z); a0[3] = f2bfs(xa.w);
        a0[4] = f2bfs(xb.x); a0[5] = f2bfs(xb.y); a0[6] = f2bfs(xb.z); a0[7] = f2bfs(xb.w);
        a1[0] = f2bfs(xc.x); a1[1] = f2bfs(xc.y); a1[2] = f2bfs(xc.z); a1[3] = f2bfs(xc.w);
        a1[4] = f2bfs(xd.x); a1[5] = f2bfs(xd.y); a1[6] = f2bfs(xd.z); a1[7] = f2bfs(xd.w);
        acc0 = __builtin_amdgcn_mfma_f32_16x16x32_bf16(a0, bfr, acc0, 0, 0, 0);
        acc1 = __builtin_amdgcn_mfma_f32_16x16x32_bf16(a1, bfr, acc1, 0, 0, 0);
    }
    // deterministic cross-wave reduce: D[crow=(lane>>4)*4+r][kcol=lane&15]
    __shared__ float red[4][2][16][16];
    #pragma unroll
    for (int r = 0; r < 4; ++r) {
        red[wave][0][lgrp*4 + r][lrow] = acc0[r];
        red[wave][1][lgrp*4 + r][lrow] = acc1[r];
    }
    __syncthreads();
    for (int i = tid; i < 512; i += 256) {
        int cg = i >> 8, rr = (i >> 4) & 15, kk = i & 15;
        float s = red[0][cg][rr][kk] + red[1][cg][rr][kk]
                + red[2][cg][rr][kk] + red[3][cg][rr][kk];
        partials[(((size_t)(2*gpair+cg))*8 + split)*256 + rr*16 + kk] = s;
    }
}

// -------------------- kernel 3: feat (reduce 8 splits) + per-cavity MLP + qkv --------------------
// grid = B*K blocks, 256 threads
__global__ void mlp_kernel(const float* __restrict__ partials,
                           const int* __restrict__ counts,
                           const float* __restrict__ w1,
                           const float* __restrict__ b1,
                           const float* __restrict__ w2,
                           const float* __restrict__ b2,
                           const float* __restrict__ in_w,
                           const float* __restrict__ in_b,
                           float* __restrict__ qkv_out) {
    int b = blockIdx.x / K_, k = blockIdx.x % K_;
    int tid = threadIdx.x;
    __shared__ float feat[C_];
    __shared__ float h[C2_];
    __shared__ float pr[C_];
    int cnt = counts[k];
    float inv = (cnt > 0) ? (1.f / (float)cnt) : 0.f;
    if (tid < C_) {
        int cg = b*8 + (tid >> 4), rr = tid & 15;
        const float* pp = partials + ((size_t)cg*8)*256 + rr*16 + k;
        float s = 0.f;
        #pragma unroll
        for (int sp = 0; sp < 8; ++sp) s += pp[sp*256];
        feat[tid] = s * inv;
    }
    __syncthreads();
    {
        const float* w1r = w1 + ((size_t)k*C2_ + tid)*C_;
        float a = b1[k*C2_ + tid];
        #pragma unroll 8
        for (int c = 0; c < C_; ++c) a += feat[c] * w1r[c];
        h[tid] = fmaxf(a, 0.f);
    }
    __syncthreads();
    if (tid < C_) {
        const float* w2r = w2 + ((size_t)k*C_ + tid)*C2_;
        float a = b2[k*C_ + tid];
        #pragma unroll 8
        for (int d = 0; d < C2_; ++d) a += h[d] * w2r[d];
        pr[tid] = tanhf(a);
    }
    __syncthreads();
    for (int e = tid; e < E3_; e += 256) {
        const float* wr = in_w + (size_t)e*C_;
        float a = in_b[e];
        #pragma unroll 8
        for (int c = 0; c < C_; ++c) a += pr[c] * wr[c];
        qkv_out[((size_t)b*K_ + k)*E3_ + e] = a;
    }
}

// -------------------- kernel 4: MHA over K cavities + out proj --------------------
// grid = B blocks, 256 threads
__global__ void attn_kernel(const float* __restrict__ qkv_in,
                            const float* __restrict__ out_w,
                            const float* __restrict__ out_b,
                            float* __restrict__ att) {
    int b = blockIdx.x;
    int tid = threadIdx.x;
    __shared__ float qkv[K_][E3_];
    __shared__ float ov[K_][C_];
    for (int i = tid; i < K_*E3_; i += 256) qkv[i / E3_][i % E3_] = qkv_in[(size_t)b*K_*E3_ + i];
    __syncthreads();
    if (tid < H_*K_) {
        int hh = tid / K_, q = tid % K_;
        const float* qv = &qkv[q][hh*DH_];
        float sc[K_];
        float mx = -1e30f;
        #pragma unroll
        for (int kk = 0; kk < K_; ++kk) {
            float a = 0.f;
            #pragma unroll
            for (int d = 0; d < DH_; ++d) a += qv[d] * qkv[kk][C_ + hh*DH_ + d];
            a *= 0.25f;
            sc[kk] = a;
            mx = fmaxf(mx, a);
        }
        float ssum = 0.f;
        #pragma unroll
        for (int kk = 0; kk < K_; ++kk) { sc[kk] = __expf(sc[kk] - mx); ssum += sc[kk]; }
        float rinv = 1.f / ssum;
        #pragma unroll
        for (int d = 0; d < DH_; ++d) {
            float a = 0.f;
            #pragma unroll
            for (int kk = 0; kk < K_; ++kk) a += sc[kk] * qkv[kk][2*C_ + hh*DH_ + d];
            ov[q][hh*DH_ + d] = a * rinv;
        }
    }
    __syncthreads();
    for (int i = tid; i < K_*C_; i += 256) {
        int kk = i / C_, o = i % C_;
        const float* wr = out_w + (size_t)o*C_;
        float a = out_b[o];
        #pragma unroll 8
        for (int c = 0; c < C_; ++c) a += ov[kk][c] * wr[c];
        att[((size_t)b*K_ + kk)*C_ + o] = a;
    }
}

// -------------------- kernel 5: gather-add, 4 rows/block, reverse-streamed --------------------
// grid = (13, 256), 256 threads
__global__ void gather_kernel(const float* __restrict__ x,
                              const float* __restrict__ att,
                              const unsigned char* __restrict__ nearest,
                              float* __restrict__ out) {
    int r0 = blockIdx.y * 4;          // 4 consecutive rows, same b (128 % 4 == 0)
    int b = r0 >> 7;
    __shared__ float al[4][K_];
    if (threadIdx.x < 4*K_) {
        int r = threadIdx.x / K_, kk = threadIdx.x % K_;
        al[r][kk] = att[((size_t)b*K_ + kk)*C_ + ((r0 + r) & (C_-1))];
    }
    __syncthreads();
    const float4* xr0 = (const float4*)(x + (size_t)(r0+0) * P_);
    const float4* xr1 = (const float4*)(x + (size_t)(r0+1) * P_);
    const float4* xr2 = (const float4*)(x + (size_t)(r0+2) * P_);
    const float4* xr3 = (const float4*)(x + (size_t)(r0+3) * P_);
    float4* o0 = (float4*)(out + (size_t)(r0+0) * P_);
    float4* o1 = (float4*)(out + (size_t)(r0+1) * P_);
    float4* o2 = (float4*)(out + (size_t)(r0+2) * P_);
    float4* o3 = (float4*)(out + (size_t)(r0+3) * P_);
    const uchar4* nr = (const uchar4*)nearest;
    for (int j = blockIdx.x * blockDim.x + threadIdx.x; j < P_/4; j += 13*256) {
        int i = P_/4 - 1 - j;         // tail-first
        uchar4 nv = nr[i];
        float4 x0 = xr0[i], x1 = xr1[i], x2 = xr2[i], x3 = xr3[i];
        float4 v0, v1, v2, v3;
        v0.x = x0.x + al[0][nv.x]; v0.y = x0.y + al[0][nv.y]; v0.z = x0.z + al[0][nv.z]; v0.w = x0.w + al[0][nv.w];
        v1.x = x1.x + al[1][nv.x]; v1.y = x1.y + al[1][nv.y]; v1.z = x1.z + al[1][nv.z]; v1.w = x1.w + al[1][nv.w];
        v2.x = x2.x + al[2][nv.x]; v2.y = x2.y + al[2][nv.y]; v2.z = x2.z + al[2][nv.z]; v2.w = x2.w + al[2][nv.w];
        v3.x = x3.x + al[3][nv.x]; v3.y = x3.y + al[3][nv.y]; v3.z = x3.z + al[3][nv.z]; v3.w = x3.w + al[3][nv.w];
        o0[i] = v0; o1[i] = v1; o2[i] = v2; o3[i] = v3;
    }
}

extern "C" void kernel_launch(void* const* d_in, const int* in_sizes, int n_in,
                              void* d_out, int out_size, void* d_ws, size_t ws_size,
                              hipStream_t stream) {
    const float* x      = (const float*)d_in[0];
    const float* points = (const float*)d_in[1];
    const float* cav    = (const float*)d_in[2];
    const float* w1     = (const float*)d_in[3];
    const float* b1     = (const float*)d_in[4];
    const float* w2     = (const float*)d_in[5];
    const float* b2     = (const float*)d_in[6];
    const float* in_w   = (const float*)d_in[7];
    const float* in_b   = (const float*)d_in[8];
    const float* out_w  = (const float*)d_in[9];
    const float* out_b  = (const float*)d_in[10];
    float* out = (float*)d_out;

    // workspace carve (all offsets 256B-aligned)
    char* w = (char*)d_ws;
    unsigned short* mask    = (unsigned short*)(w + 0);        // 200,000 B
    unsigned char*  nearest = (unsigned char*)(w + 200192);    // 100,000 B
    int*            counts  = (int*)(w + 300288);              // 56 B
    float*          partials= (float*)(w + 300544);            // 64*8*256*4 = 524,288 B
    float*          qkv     = (float*)(w + 824832);            // 172,032 B
    float*          att     = (float*)(w + 996864);            // 57,344 B

    (void)hipMemsetAsync(counts, 0, K_ * sizeof(int), stream);
    geom_kernel<<<(P_ + 255)/256, 256, 0, stream>>>(points, cav, mask, nearest, counts);
    pool_mfma_kernel<<<256, 256, 0, stream>>>(x, mask, partials);
    mlp_kernel<<<B_*K_, 256, 0, stream>>>(partials, counts, w1, b1, w2, b2, in_w, in_b, qkv);
    attn_kernel<<<B_, 256, 0, stream>>>(qkv, out_w, out_b, att);
    gather_kernel<<<dim3(13, 256), 256, 0, stream>>>(x, att, nearest, out);
}

// Round 11
// 318.562 us; speedup vs baseline: 1.1679x; 1.0161x over previous
//
#include <hip/hip_runtime.h>
#include <hip/hip_bf16.h>
#include <math.h>

#define B_ 8
#define C_ 128
#define P_ 100000
#define K_ 14
#define H_ 8
#define DH_ 16
#define C2_ (2*C_)
#define E3_ (3*C_)
#define R2 0.25f

__device__ __forceinline__ int bitsel(unsigned m, int k) {
#if __has_builtin(__builtin_amdgcn_sbfe)
    return __builtin_amdgcn_sbfe((int)m, (unsigned)k, 1u);
#else
    return ((int)(m << (31 - k))) >> 31;
#endif
}

// -------------------- kernel 1: geometry -> u16 mask + nearest + counts --------------------
__global__ void geom_kernel(const float* __restrict__ pts,
                            const float* __restrict__ cav,
                            unsigned short* __restrict__ mask,
                            unsigned char* __restrict__ nearest,
                            int* __restrict__ counts) {
    __shared__ float cx[K_], cy[K_], cz[K_];
    __shared__ int sm[K_];
    int tid = threadIdx.x;
    if (tid < K_) {
        cx[tid] = cav[tid*3+0];
        cy[tid] = cav[tid*3+1];
        cz[tid] = cav[tid*3+2];
        sm[tid] = 0;
    }
    __syncthreads();
    int p = blockIdx.x * blockDim.x + tid;
    bool valid = (p < P_);
    int pc = valid ? p : (P_ - 1);
    float px = pts[pc*3+0], py = pts[pc*3+1], pz = pts[pc*3+2];
    unsigned m = 0;
    float best = 1e30f;
    int bi = 0;
    #pragma unroll
    for (int k = 0; k < K_; ++k) {
        float dx = px - cx[k], dy = py - cy[k], dz = pz - cz[k];
        float d2 = dx*dx + dy*dy + dz*dz;
        if (d2 < R2) m |= (1u << k);
        if (d2 < best) { best = d2; bi = k; }
    }
    if (valid) {
        mask[p] = (unsigned short)m;
        nearest[p] = (unsigned char)bi;
    }
    int lane = tid & 63;
    #pragma unroll
    for (int k = 0; k < K_; ++k) {
        unsigned long long bal = __ballot(valid && ((m >> k) & 1u));
        if (lane == 0) atomicAdd(&sm[k], (int)__popcll(bal));
    }
    __syncthreads();
    if (tid < K_) atomicAdd(&counts[tid], sm[tid]);
}

// -------------------- kernel 2: masked pooling, u16 masks, decode shared over 4 rows --------------------
// grid = 256 blocks; 512 threads; each block owns 4 consecutive (b,c) rows.  (exact R5)
__global__ __launch_bounds__(512) void pool_kernel(const float* __restrict__ x,
                                                   const unsigned short* __restrict__ mask,
                                                   float* __restrict__ sums) {
    int r0 = blockIdx.x * 4;
    int tid = threadIdx.x;
    const float4* xr0 = (const float4*)(x + (size_t)(r0+0) * P_);
    const float4* xr1 = (const float4*)(x + (size_t)(r0+1) * P_);
    const float4* xr2 = (const float4*)(x + (size_t)(r0+2) * P_);
    const float4* xr3 = (const float4*)(x + (size_t)(r0+3) * P_);
    const ushort4* mr = (const ushort4*)mask;
    float acc[4][K_];
    #pragma unroll
    for (int r = 0; r < 4; ++r)
        #pragma unroll
        for (int k = 0; k < K_; ++k) acc[r][k] = 0.f;
    for (int i = tid; i < P_/4; i += 512) {
        ushort4 mv = mr[i];
        unsigned ma = mv.x, mb = mv.y, mc = mv.z, md = mv.w;
        float4 xv0 = xr0[i], xv1 = xr1[i], xv2 = xr2[i], xv3 = xr3[i];
        #pragma unroll
        for (int k = 0; k < K_; ++k) {
            float m0 = __int_as_float(bitsel(ma, k) & 0x3f800000);
            float m1 = __int_as_float(bitsel(mb, k) & 0x3f800000);
            float m2 = __int_as_float(bitsel(mc, k) & 0x3f800000);
            float m3 = __int_as_float(bitsel(md, k) & 0x3f800000);
            acc[0][k] = fmaf(xv0.x, m0, fmaf(xv0.y, m1, fmaf(xv0.z, m2, fmaf(xv0.w, m3, acc[0][k]))));
            acc[1][k] = fmaf(xv1.x, m0, fmaf(xv1.y, m1, fmaf(xv1.z, m2, fmaf(xv1.w, m3, acc[1][k]))));
            acc[2][k] = fmaf(xv2.x, m0, fmaf(xv2.y, m1, fmaf(xv2.z, m2, fmaf(xv2.w, m3, acc[2][k]))));
            acc[3][k] = fmaf(xv3.x, m0, fmaf(xv3.y, m1, fmaf(xv3.z, m2, fmaf(xv3.w, m3, acc[3][k]))));
        }
    }
    int lane = tid & 63, wave = tid >> 6;
    __shared__ float lsum[8][4][K_];
    #pragma unroll
    for (int r = 0; r < 4; ++r) {
        #pragma unroll
        for (int k = 0; k < K_; ++k) {
            float v = acc[r][k];
            #pragma unroll
            for (int off = 32; off > 0; off >>= 1) v += __shfl_down(v, off);
            if (lane == 0) lsum[wave][r][k] = v;
        }
    }
    __syncthreads();
    if (tid < 4*K_) {
        int r = tid / K_, k = tid % K_;
        float t = 0.f;
        #pragma unroll
        for (int w = 0; w < 8; ++w) t += lsum[w][r][k];
        int row = r0 + r;
        int b = row >> 7, c = row & (C_-1);
        sums[((size_t)b*K_ + k)*C_ + c] = t;
    }
}

// -------------------- kernel 3: feat + per-cavity MLP + qkv projection --------------------
// grid = B*K blocks, 256 threads  (exact R5)
__global__ void mlp_kernel(const float* __restrict__ sums,
                           const int* __restrict__ counts,
                           const float* __restrict__ w1,
                           const float* __restrict__ b1,
                           const float* __restrict__ w2,
                           const float* __restrict__ b2,
                           const float* __restrict__ in_w,
                           const float* __restrict__ in_b,
                           float* __restrict__ qkv_out) {
    int b = blockIdx.x / K_, k = blockIdx.x % K_;
    int tid = threadIdx.x;
    __shared__ float feat[C_];
    __shared__ float h[C2_];
    __shared__ float pr[C_];
    int cnt = counts[k];
    float inv = (cnt > 0) ? (1.f / (float)cnt) : 0.f;
    if (tid < C_) feat[tid] = sums[((size_t)b*K_ + k)*C_ + tid] * inv;
    __syncthreads();
    {
        const float* w1r = w1 + ((size_t)k*C2_ + tid)*C_;
        float a = b1[k*C2_ + tid];
        #pragma unroll 8
        for (int c = 0; c < C_; ++c) a += feat[c] * w1r[c];
        h[tid] = fmaxf(a, 0.f);
    }
    __syncthreads();
    if (tid < C_) {
        const float* w2r = w2 + ((size_t)k*C_ + tid)*C2_;
        float a = b2[k*C_ + tid];
        #pragma unroll 8
        for (int d = 0; d < C2_; ++d) a += h[d] * w2r[d];
        pr[tid] = tanhf(a);
    }
    __syncthreads();
    for (int e = tid; e < E3_; e += 256) {
        const float* wr = in_w + (size_t)e*C_;
        float a = in_b[e];
        #pragma unroll 8
        for (int c = 0; c < C_; ++c) a += pr[c] * wr[c];
        qkv_out[((size_t)b*K_ + k)*E3_ + e] = a;
    }
}

// -------------------- kernel 4: MHA over K cavities + out proj --------------------
// grid = B blocks, 256 threads  (exact R5)
__global__ void attn_kernel(const float* __restrict__ qkv_in,
                            const float* __restrict__ out_w,
                            const float* __restrict__ out_b,
                            float* __restrict__ att) {
    int b = blockIdx.x;
    int tid = threadIdx.x;
    __shared__ float qkv[K_][E3_];
    __shared__ float ov[K_][C_];
    for (int i = tid; i < K_*E3_; i += 256) qkv[i / E3_][i % E3_] = qkv_in[(size_t)b*K_*E3_ + i];
    __syncthreads();
    if (tid < H_*K_) {
        int hh = tid / K_, q = tid % K_;
        const float* qv = &qkv[q][hh*DH_];
        float sc[K_];
        float mx = -1e30f;
        #pragma unroll
        for (int kk = 0; kk < K_; ++kk) {
            float a = 0.f;
            #pragma unroll
            for (int d = 0; d < DH_; ++d) a += qv[d] * qkv[kk][C_ + hh*DH_ + d];
            a *= 0.25f;
            sc[kk] = a;
            mx = fmaxf(mx, a);
        }
        float ssum = 0.f;
        #pragma unroll
        for (int kk = 0; kk < K_; ++kk) { sc[kk] = __expf(sc[kk] - mx); ssum += sc[kk]; }
        float rinv = 1.f / ssum;
        #pragma unroll
        for (int d = 0; d < DH_; ++d) {
            float a = 0.f;
            #pragma unroll
            for (int kk = 0; kk < K_; ++kk) a += sc[kk] * qkv[kk][2*C_ + hh*DH_ + d];
            ov[q][hh*DH_ + d] = a * rinv;
        }
    }
    __syncthreads();
    for (int i = tid; i < K_*C_; i += 256) {
        int kk = i / C_, o = i % C_;
        const float* wr = out_w + (size_t)o*C_;
        float a = out_b[o];
        #pragma unroll 8
        for (int c = 0; c < C_; ++c) a += ov[kk][c] * wr[c];
        att[((size_t)b*K_ + kk)*C_ + o] = a;
    }
}

// -------------------- kernel 5: gather-add, reverse-streamed, 4x-replicated LDS table --------------------
// grid = (13, B*C), 256 threads  (R5 + bank-conflict fix)
__global__ void gather_kernel(const float* __restrict__ x,
                              const float* __restrict__ att,
                              const unsigned char* __restrict__ nearest,
                              float* __restrict__ out) {
    int row = blockIdx.y;            // b*C + c
    int b = row >> 7, c = row & (C_-1);
    // 4-way replicated table: al[k*4 + r], r = lane&3 -> spreads 14 entries
    // over 56 LDS slots (28+ banks) instead of 14 banks.
    __shared__ float al[K_*4];
    if (threadIdx.x < K_*4) {
        int kk = threadIdx.x >> 2;
        al[threadIdx.x] = att[((size_t)b*K_ + kk)*C_ + c];
    }
    __syncthreads();
    int rsel = threadIdx.x & 3;
    const float4* xr = (const float4*)(x + (size_t)row * P_);
    float4* orow = (float4*)(out + (size_t)row * P_);
    const uchar4* nr = (const uchar4*)nearest;
    for (int j = blockIdx.x * blockDim.x + threadIdx.x; j < P_/4; j += 13*256) {
        int i = P_/4 - 1 - j;        // tail-first (exact R5 order)
        float4 xv = xr[i];
        uchar4 nv = nr[i];
        float4 o;
        o.x = xv.x + al[nv.x*4 + rsel];
        o.y = xv.y + al[nv.y*4 + rsel];
        o.z = xv.z + al[nv.z*4 + rsel];
        o.w = xv.w + al[nv.w*4 + rsel];
        orow[i] = o;
    }
}

extern "C" void kernel_launch(void* const* d_in, const int* in_sizes, int n_in,
                              void* d_out, int out_size, void* d_ws, size_t ws_size,
                              hipStream_t stream) {
    const float* x      = (const float*)d_in[0];
    const float* points = (const float*)d_in[1];
    const float* cav    = (const float*)d_in[2];
    const float* w1     = (const float*)d_in[3];
    const float* b1     = (const float*)d_in[4];
    const float* w2     = (const float*)d_in[5];
    const float* b2     = (const float*)d_in[6];
    const float* in_w   = (const float*)d_in[7];
    const float* in_b   = (const float*)d_in[8];
    const float* out_w  = (const float*)d_in[9];
    const float* out_b  = (const float*)d_in[10];
    float* out = (float*)d_out;

    // workspace carve (all offsets 256B-aligned)
    char* w = (char*)d_ws;
    unsigned short* mask    = (unsigned short*)(w + 0);        // 200,000 B
    unsigned char*  nearest = (unsigned char*)(w + 200192);    // 100,000 B
    int*            counts  = (int*)(w + 300288);              // 56 B
    float*          sums    = (float*)(w + 300544);            // 57,344 B
    float*          qkv     = (float*)(w + 358144);            // 172,032 B
    float*          att     = (float*)(w + 530432);            // 57,344 B

    (void)hipMemsetAsync(counts, 0, K_ * sizeof(int), stream);
    geom_kernel<<<(P_ + 255)/256, 256, 0, stream>>>(points, cav, mask, nearest, counts);
    pool_kernel<<<256, 512, 0, stream>>>(x, mask, sums);
    mlp_kernel<<<B_*K_, 256, 0, stream>>>(sums, counts, w1, b1, w2, b2, in_w, in_b, qkv);
    attn_kernel<<<B_, 256, 0, stream>>>(qkv, out_w, out_b, att);
    gather_kernel<<<dim3(13, B_*C_), 256, 0, stream>>>(x, att, nearest, out);
}